// Round 5
// baseline (87.611 us; speedup 1.0000x reference)
//
#include <hip/hip_runtime.h>

#define MAXT 100000.0f

constexpr int B    = 64;
constexpr int IN   = 1024;
constexpr int N    = 1025;   // IN + bias column
constexpr int OUTS = 512;
constexpr int NSEG = 16;     // segment-waves per block (1024 threads)
constexpr int SEGL = 64;     // uniform segment length; i=1024 is seg-15 tail
constexpr unsigned KEYMASK = 0xFFFFFC00u;  // top 22 value bits | 10-bit index
constexpr unsigned BIASKEY = 0x3F8003FFu;  // key upper bound for bias rank

struct alignas(8) Pair { unsigned off; unsigned x; };

// ---------------- Fused kernel: per-row sort + gathered-weight scan ---------
// grid = (B, OUTS/64), block = (64 j-lanes, 16 segment-waves) = 1024 threads.
// Phase A: each block independently argsorts row b (8-way redundant across
//   j-chunks, but it runs on CUs that a standalone sort would leave idle):
//   1-elem/thread bitonic; distance<64 stages via __shfl_xor (barrier-free),
//   the 10 distance>=64 stages via LDS. Bias inserted by rank
//   (__syncthreads_count). ps/xsh built directly in LDS -- no global
//   round-trip, no second launch.
// Phase B: segmented scan. Valid candidate at step i lies in [xs_i,xs_{i+1}]
//   and xs is sorted => filtered min == FIRST valid candidate. wc starts at
//   -1 so it holds w_cum-1. Weights register-cached in pass 1 so pass 2 does
//   no global loads.
__global__ __launch_bounds__(1024, 4) void snn_fused(
    const float* __restrict__ layer_in,
    const float* __restrict__ weight,
    const float* __restrict__ delay,
    float* __restrict__ out) {
  __shared__ unsigned ksh[IN];
  __shared__ float vsh[IN];
  __shared__ __align__(16) Pair ps[N + 1];
  __shared__ float xsh[N + 1];
  __shared__ float psw [NSEG][64];
  __shared__ float pswx[NSEG][64];

  const int b    = blockIdx.x;
  const int jc   = blockIdx.y;
  const int lane = threadIdx.x;          // j column
  const int seg  = threadIdx.y;          // i segment
  const int tid  = seg * 64 + lane;
  const int j    = jc * 64 + lane;
  const unsigned jadd = (unsigned)(j * 4);

  // ---- Phase A: scaled input + bitonic argsort ----
  {
    float d = delay[tid];
    float v = layer_in[b * IN + tid] * expf(d > 0.0f ? d : 0.0f);
    vsh[tid] = v;                                 // exact x, gathered at end
    unsigned k = (__float_as_uint(v) & KEYMASK) | (unsigned)tid;

    for (int kk = 2; kk <= IN; kk <<= 1) {
      for (int jj = kk >> 1; jj > 0; jj >>= 1) {
        unsigned other;
        if (jj >= 64) {              // cross-wave exchange via LDS
          __syncthreads();           // WAR vs previous stage's reads
          ksh[tid] = k;
          __syncthreads();
          other = ksh[tid ^ jj];
        } else {                     // in-wave exchange, barrier-free
          other = __shfl_xor(k, jj, 64);
        }
        bool up    = ((tid & kk) == 0);
        bool lower = ((tid & jj) == 0);
        unsigned mn = k < other ? k : other;
        unsigned mx = k < other ? other : k;
        k = (up == lower) ? mn : mx;
      }
    }

    // bias (x=1.0, idx=IN) rank = #elements sorting before it (stable order)
    int r = __syncthreads_count((k <= BIASKEY) ? 1 : 0);

    int idx = (int)(k & 1023u);
    float x = vsh[idx];
    int pos = tid + (tid >= r);
    Pair pr; pr.off = (unsigned)(idx * OUTS * 4); pr.x = __float_as_uint(x);
    ps[pos] = pr;
    xsh[pos] = x;
    if (tid == 0) {
      Pair bias; bias.off = (unsigned)(IN * OUTS * 4); bias.x = __float_as_uint(1.0f);
      ps[r] = bias; xsh[r] = 1.0f;
      Pair sent; sent.off = 0u; sent.x = __float_as_uint(MAXT);
      ps[N] = sent; xsh[N] = MAXT;
    }
    __syncthreads();
  }

  // ---- Phase B: segmented scan, first-valid latch ----
  const char* wbase = (const char*)weight;
  const int is = seg * SEGL;

  // Pass 1: partial sums; weights land in registers for pass 2.
  float wcache[SEGL];
  float pw = 0.0f, pwx = 0.0f;
#pragma unroll
  for (int u = 0; u < SEGL; ++u) {
    Pair p = ps[is + u];
    float w = *(const float*)(wbase + (p.off + jadd));
    wcache[u] = w;
    pw  += w;
    pwx = fmaf(w, __uint_as_float(p.x), pwx);
  }
  psw [seg][lane] = pw;
  pswx[seg][lane] = pwx;
  __syncthreads();

  // Exclusive prefix over segments; wc holds w_cum - 1.
  float wc = -1.0f, wi = 0.0f;
  for (int s = 0; s < seg; ++s) { wc += psw[s][lane]; wi += pswx[s][lane]; }

  // Pass 2: latch first valid candidate (bden < 0 encodes "not found").
  float bnum = MAXT, bden = -1.0f;
  float xi = xsh[is];
#pragma unroll
  for (int u = 0; u < SEGL; ++u) {
    float w  = wcache[u];
    float xn = xsh[is + u + 1];
    wc += w;
    wi = fmaf(w, xi, wi);
    float s1 = fmaf(-xi, wc, wi);            // wi - xi*(w_cum-1)
    float s2 = fmaf(xn, wc, -wi);            // xn*(w_cum-1) - wi
    float m  = fminf(fminf(wc, s1), s2);     // v_min3
    bool upd = (m >= 0.0f) & (bden < 0.0f);
    bnum = upd ? wi : bnum;
    bden = upd ? wc : bden;
    xi = xn;
  }
  if (seg == NSEG - 1) {                     // tail element i = 1024
    Pair p = ps[N - 1];
    float w  = *(const float*)(wbase + (p.off + jadd));
    float xn = xsh[N];                       // MAXT sentinel
    wc += w;
    wi = fmaf(w, xi, wi);
    float s1 = fmaf(-xi, wc, wi);
    float s2 = fmaf(xn, wc, -wi);
    float m  = fminf(fminf(wc, s1), s2);
    bool upd = (m >= 0.0f) & (bden < 0.0f);
    bnum = upd ? wi : bnum;
    bden = upd ? wc : bden;
  }
  float best = (bden < 0.0f) ? MAXT : bnum / fmaxf(bden, 1e-10f);

  __syncthreads();
  psw[seg][lane] = best;
  __syncthreads();
  if (seg == 0) {
    float m = psw[0][lane];
#pragma unroll
    for (int s = 1; s < NSEG; ++s) m = fminf(m, psw[s][lane]);
    out[b * OUTS + j] = m;
  }
}

extern "C" void kernel_launch(void* const* d_in, const int* in_sizes, int n_in,
                              void* d_out, int out_size, void* d_ws, size_t ws_size,
                              hipStream_t stream) {
  const float* layer_in = (const float*)d_in[0];
  const float* weight   = (const float*)d_in[1];
  const float* delay    = (const float*)d_in[2];
  float* out = (float*)d_out;
  (void)d_ws; (void)ws_size;

  snn_fused<<<dim3(B, OUTS / 64), dim3(64, NSEG), 0, stream>>>(
      layer_in, weight, delay, out);
}

// Round 6
// 83.754 us; speedup vs baseline: 1.0461x; 1.0461x over previous
//
#include <hip/hip_runtime.h>

#define MAXT 100000.0f

constexpr int B    = 64;
constexpr int IN   = 1024;
constexpr int N    = 1025;   // IN + bias column
constexpr int OUTS = 512;
constexpr int NSEG = 16;     // segment-waves per block (1024 threads)
constexpr int SEGL = 64;     // uniform segment length; i=1024 is seg-15 tail
constexpr unsigned KEYMASK = 0xFFFFFC00u;  // top 22 value bits | 10-bit index
constexpr unsigned BIASKEY = 0x3F8003FFu;  // key upper bound for bias rank

struct alignas(8) Pair { unsigned off; unsigned x; };

// ---------------- Fused: per-row sort + gathered-weight scan, 2 j/thread ----
// grid = (B, 4) = 256 blocks -> ONE block-round on 256 CUs (the R5 version's
// 512 blocks ran 2 sequential rounds, paying the redundant sort twice).
// Each block: sort row b once (4-way redundant across j-chunks; wall cost
// equals the standalone sort, which only occupied 64 CUs), then scan 128 j
// columns, 2 per thread via float2 weight loads (shares LDS broadcasts and
// loop overhead across both j). No wcache: pass-2 reloads from L2-hot weight,
// keeping VGPR low (R4's wcache[64] risked spills under the 128-VGPR cap).
__global__ __launch_bounds__(1024, 4) void snn_fused(
    const float* __restrict__ layer_in,
    const float* __restrict__ weight,
    const float* __restrict__ delay,
    float* __restrict__ out) {
  __shared__ unsigned ksh[IN];
  __shared__ float vsh[IN];
  __shared__ __align__(16) Pair ps[N + 1];
  __shared__ float xsh[N + 1];
  __shared__ float2 red[NSEG][64];     // pass-1 partials / final reduction

  const int b    = blockIdx.x;
  const int jc   = blockIdx.y;
  const int lane = threadIdx.x;        // j pair
  const int seg  = threadIdx.y;        // i segment
  const int tid  = seg * 64 + lane;
  const unsigned jadd = (unsigned)((jc * 128 + lane * 2) * 4);  // byte offset

  // ---- Phase A: scaled input + 1-elem/thread bitonic argsort ----
  {
    float d = delay[tid];
    float v = layer_in[b * IN + tid] * expf(d > 0.0f ? d : 0.0f);
    vsh[tid] = v;                                 // exact x, gathered at end
    unsigned k = (__float_as_uint(v) & KEYMASK) | (unsigned)tid;

    for (int kk = 2; kk <= IN; kk <<= 1) {
      for (int jj = kk >> 1; jj > 0; jj >>= 1) {
        unsigned other;
        if (jj >= 64) {              // cross-wave exchange via LDS
          __syncthreads();           // WAR vs previous stage's reads
          ksh[tid] = k;
          __syncthreads();
          other = ksh[tid ^ jj];
        } else {                     // in-wave exchange, barrier-free
          other = __shfl_xor(k, jj, 64);
        }
        bool up    = ((tid & kk) == 0);
        bool lower = ((tid & jj) == 0);
        unsigned mn = k < other ? k : other;
        unsigned mx = k < other ? other : k;
        k = (up == lower) ? mn : mx;
      }
    }

    // bias (x=1.0, idx=IN) rank = #elements sorting before it (stable order)
    int r = __syncthreads_count((k <= BIASKEY) ? 1 : 0);

    int idx = (int)(k & 1023u);
    float x = vsh[idx];
    int pos = tid + (tid >= r);
    Pair pr; pr.off = (unsigned)(idx * OUTS * 4); pr.x = __float_as_uint(x);
    ps[pos] = pr;
    xsh[pos] = x;
    if (tid == 0) {
      Pair bias; bias.off = (unsigned)(IN * OUTS * 4); bias.x = __float_as_uint(1.0f);
      ps[r] = bias; xsh[r] = 1.0f;
      Pair sent; sent.off = 0u; sent.x = __float_as_uint(MAXT);
      ps[N] = sent; xsh[N] = MAXT;
    }
    __syncthreads();
  }

  // ---- Phase B: segmented scan, first-valid latch, 2 j per thread ----
  const char* wbase = (const char*)weight;
  const int is = seg * SEGL;

  // Pass 1: per-segment partial sums of (w, w*x) for both j.
  float pw0 = 0.0f, pw1 = 0.0f, px0 = 0.0f, px1 = 0.0f;
#pragma unroll 4
  for (int u = 0; u < SEGL; ++u) {
    Pair p = ps[is + u];
    float2 w = *(const float2*)(wbase + (p.off + jadd));
    float xv = __uint_as_float(p.x);
    pw0 += w.x; pw1 += w.y;
    px0 = fmaf(w.x, xv, px0);
    px1 = fmaf(w.y, xv, px1);
  }
  red[seg][lane] = make_float2(pw0, pw1);
  __syncthreads();
  float2 acc_w = make_float2(-1.0f, -1.0f);   // holds w_cum - 1
  {
    float a0 = -1.0f, a1 = -1.0f;
    for (int s = 0; s < seg; ++s) { float2 t = red[s][lane]; a0 += t.x; a1 += t.y; }
    acc_w.x = a0; acc_w.y = a1;
  }
  __syncthreads();
  red[seg][lane] = make_float2(px0, px1);
  __syncthreads();
  float wi0 = 0.0f, wi1 = 0.0f;
  for (int s = 0; s < seg; ++s) { float2 t = red[s][lane]; wi0 += t.x; wi1 += t.y; }
  float wc0 = acc_w.x, wc1 = acc_w.y;

  // Pass 2: latch first valid candidate per j (bden<0 encodes "not found").
  // Valid at step i <=> min3(wc, wi - xi*wc, xn*wc - wi) >= 0; since xs is
  // sorted, the first valid candidate IS the filtered min.
  float bn0 = MAXT, bd0 = -1.0f, bn1 = MAXT, bd1 = -1.0f;
  float xi = xsh[is];
#pragma unroll 4
  for (int u = 0; u < SEGL; ++u) {
    Pair p = ps[is + u];
    float2 w = *(const float2*)(wbase + (p.off + jadd));
    float xn = xsh[is + u + 1];
    wc0 += w.x;
    wi0 = fmaf(w.x, xi, wi0);
    float m0 = fminf(fminf(wc0, fmaf(-xi, wc0, wi0)), fmaf(xn, wc0, -wi0));
    bool u0 = (m0 >= 0.0f) & (bd0 < 0.0f);
    bn0 = u0 ? wi0 : bn0;
    bd0 = u0 ? wc0 : bd0;
    wc1 += w.y;
    wi1 = fmaf(w.y, xi, wi1);
    float m1 = fminf(fminf(wc1, fmaf(-xi, wc1, wi1)), fmaf(xn, wc1, -wi1));
    bool u1 = (m1 >= 0.0f) & (bd1 < 0.0f);
    bn1 = u1 ? wi1 : bn1;
    bd1 = u1 ? wc1 : bd1;
    xi = xn;
  }
  if (seg == NSEG - 1) {                     // tail element i = 1024
    Pair p = ps[N - 1];
    float2 w = *(const float2*)(wbase + (p.off + jadd));
    float xn = xsh[N];                       // MAXT sentinel
    wc0 += w.x;
    wi0 = fmaf(w.x, xi, wi0);
    float m0 = fminf(fminf(wc0, fmaf(-xi, wc0, wi0)), fmaf(xn, wc0, -wi0));
    bool u0 = (m0 >= 0.0f) & (bd0 < 0.0f);
    bn0 = u0 ? wi0 : bn0;
    bd0 = u0 ? wc0 : bd0;
    wc1 += w.y;
    wi1 = fmaf(w.y, xi, wi1);
    float m1 = fminf(fminf(wc1, fmaf(-xi, wc1, wi1)), fmaf(xn, wc1, -wi1));
    bool u1 = (m1 >= 0.0f) & (bd1 < 0.0f);
    bn1 = u1 ? wi1 : bn1;
    bd1 = u1 ? wc1 : bd1;
  }
  float best0 = (bd0 < 0.0f) ? MAXT : bn0 / fmaxf(bd0, 1e-10f);
  float best1 = (bd1 < 0.0f) ? MAXT : bn1 / fmaxf(bd1, 1e-10f);

  __syncthreads();
  red[seg][lane] = make_float2(best0, best1);
  __syncthreads();
  if (seg == 0) {
    float2 m = red[0][lane];
#pragma unroll
    for (int s = 1; s < NSEG; ++s) {
      float2 t = red[s][lane];
      m.x = fminf(m.x, t.x);
      m.y = fminf(m.y, t.y);
    }
    *(float2*)(&out[b * OUTS + jc * 128 + lane * 2]) = m;
  }
}

extern "C" void kernel_launch(void* const* d_in, const int* in_sizes, int n_in,
                              void* d_out, int out_size, void* d_ws, size_t ws_size,
                              hipStream_t stream) {
  const float* layer_in = (const float*)d_in[0];
  const float* weight   = (const float*)d_in[1];
  const float* delay    = (const float*)d_in[2];
  float* out = (float*)d_out;
  (void)d_ws; (void)ws_size;

  snn_fused<<<dim3(B, OUTS / 128), dim3(64, NSEG), 0, stream>>>(
      layer_in, weight, delay, out);
}

// Round 7
// 79.895 us; speedup vs baseline: 1.0966x; 1.0483x over previous
//
#include <hip/hip_runtime.h>

#define MAXT 100000.0f

constexpr int B    = 64;
constexpr int IN   = 1024;
constexpr int N    = 1025;   // IN + bias column
constexpr int OUTS = 512;
constexpr int NSEG = 16;     // segment-waves per block (1024 threads)
constexpr int SEGL = 64;     // uniform segment length; i=1024 is seg-15 tail
constexpr unsigned KEYMASK = 0xFFFFFC00u;  // top 22 value bits | 10-bit index
constexpr unsigned BIASKEY = 0x3F8003FFu;  // key upper bound for bias rank

struct alignas(8) Pair { unsigned off; unsigned x; };

// ---------------- Fused: per-row sort + gathered-weight scan, 2 j/thread ----
// grid = (B, 4) = 256 blocks -> one block-round on 256 CUs. Each block sorts
// row b (4-way redundant across j-chunks; wall cost equals a standalone sort)
// then scans 128 j columns, 2 per thread via float2 loads.
// Cost model (R6 post-mortem): kernel ~20 us = sort ~4.5 + pass1 ~3 + pass2
// ~8 + reductions ~1.5 + latency slack; harness fixed floor ~61 us.
__global__ __launch_bounds__(1024, 4) void snn_fused(
    const float* __restrict__ layer_in,
    const float* __restrict__ weight,
    const float* __restrict__ delay,
    float* __restrict__ out) {
  __shared__ unsigned ksh[IN];
  __shared__ float vsh[IN];
  __shared__ __align__(16) Pair ps[N + 1];
  __shared__ float xsh[N + 1];
  __shared__ float4 red4[NSEG][64];    // pass-1 partials / final reduction

  const int b    = blockIdx.x;
  const int jc   = blockIdx.y;
  const int lane = threadIdx.x;        // j pair
  const int seg  = threadIdx.y;        // i segment
  const int tid  = seg * 64 + lane;
  const unsigned jadd = (unsigned)((jc * 128 + lane * 2) * 4);  // byte offset

  // ---- Phase A: scaled input + 1-elem/thread bitonic argsort ----
  {
    float d = delay[tid];
    float v = layer_in[b * IN + tid] * expf(d > 0.0f ? d : 0.0f);
    vsh[tid] = v;                                 // exact x, gathered at end
    unsigned k = (__float_as_uint(v) & KEYMASK) | (unsigned)tid;

#pragma unroll
    for (int kk = 2; kk <= IN; kk <<= 1) {
#pragma unroll
      for (int jj = kk >> 1; jj > 0; jj >>= 1) {
        unsigned other;
        if (jj >= 64) {              // cross-wave exchange via LDS
          __syncthreads();           // WAR vs previous stage's reads
          ksh[tid] = k;
          __syncthreads();
          other = ksh[tid ^ jj];
        } else {                     // in-wave exchange, barrier-free
          other = __shfl_xor(k, jj, 64);
        }
        bool up    = ((tid & kk) == 0);
        bool lower = ((tid & jj) == 0);
        unsigned mn = k < other ? k : other;
        unsigned mx = k < other ? other : k;
        k = (up == lower) ? mn : mx;
      }
    }

    // bias (x=1.0, idx=IN) rank = #elements sorting before it (stable order)
    int r = __syncthreads_count((k <= BIASKEY) ? 1 : 0);

    int idx = (int)(k & 1023u);
    float x = vsh[idx];
    int pos = tid + (tid >= r);
    Pair pr; pr.off = (unsigned)(idx * OUTS * 4); pr.x = __float_as_uint(x);
    ps[pos] = pr;
    xsh[pos] = x;
    if (tid == 0) {
      Pair bias; bias.off = (unsigned)(IN * OUTS * 4); bias.x = __float_as_uint(1.0f);
      ps[r] = bias; xsh[r] = 1.0f;
      Pair sent; sent.off = 0u; sent.x = __float_as_uint(MAXT);
      ps[N] = sent; xsh[N] = MAXT;
    }
    __syncthreads();
  }

  // ---- Phase B: segmented scan, first-valid latch, 2 j per thread ----
  const char* wbase = (const char*)weight;
  const int is = seg * SEGL;

  // Pass 1: per-segment partial sums of (w, w*x) for both j.
  float pw0 = 0.0f, pw1 = 0.0f, px0 = 0.0f, px1 = 0.0f;
#pragma unroll 8
  for (int u = 0; u < SEGL; ++u) {
    Pair p = ps[is + u];
    float2 w = *(const float2*)(wbase + (p.off + jadd));
    float xv = __uint_as_float(p.x);
    pw0 += w.x; pw1 += w.y;
    px0 = fmaf(w.x, xv, px0);
    px1 = fmaf(w.y, xv, px1);
  }
  red4[seg][lane] = make_float4(pw0, pw1, px0, px1);
  __syncthreads();

  // Exclusive prefix over segments; wc holds w_cum - 1.
  float wc0 = -1.0f, wc1 = -1.0f, wi0 = 0.0f, wi1 = 0.0f;
  for (int s = 0; s < seg; ++s) {
    float4 t = red4[s][lane];
    wc0 += t.x; wc1 += t.y; wi0 += t.z; wi1 += t.w;
  }

  // Pass 2: latch first valid candidate per j (bd<0 encodes "not found").
  // Valid at step i <=> min3(wc, wi - xi*wc, xn*wc - wi) >= 0; xs sorted =>
  // the first valid candidate IS the filtered min.
  float bn0 = MAXT, bd0 = -1.0f, bn1 = MAXT, bd1 = -1.0f;
  float xi = xsh[is];
#pragma unroll 8
  for (int u = 0; u < SEGL; ++u) {
    Pair p = ps[is + u];
    float2 w = *(const float2*)(wbase + (p.off + jadd));
    float xn = xsh[is + u + 1];
    wc0 += w.x;
    wi0 = fmaf(w.x, xi, wi0);
    wc1 += w.y;
    wi1 = fmaf(w.y, xi, wi1);
    float m0 = fminf(fminf(wc0, fmaf(-xi, wc0, wi0)), fmaf(xn, wc0, -wi0));
    float m1 = fminf(fminf(wc1, fmaf(-xi, wc1, wi1)), fmaf(xn, wc1, -wi1));
    bool f0 = (bd0 < 0.0f) & (m0 >= 0.0f);
    bool f1 = (bd1 < 0.0f) & (m1 >= 0.0f);
    bn0 = f0 ? wi0 : bn0;
    bd0 = f0 ? wc0 : bd0;
    bn1 = f1 ? wi1 : bn1;
    bd1 = f1 ? wc1 : bd1;
    xi = xn;
  }
  if (seg == NSEG - 1) {                     // tail element i = 1024
    Pair p = ps[N - 1];
    float2 w = *(const float2*)(wbase + (p.off + jadd));
    float xn = xsh[N];                       // MAXT sentinel
    wc0 += w.x;
    wi0 = fmaf(w.x, xi, wi0);
    wc1 += w.y;
    wi1 = fmaf(w.y, xi, wi1);
    float m0 = fminf(fminf(wc0, fmaf(-xi, wc0, wi0)), fmaf(xn, wc0, -wi0));
    float m1 = fminf(fminf(wc1, fmaf(-xi, wc1, wi1)), fmaf(xn, wc1, -wi1));
    bool f0 = (bd0 < 0.0f) & (m0 >= 0.0f);
    bool f1 = (bd1 < 0.0f) & (m1 >= 0.0f);
    bn0 = f0 ? wi0 : bn0;
    bd0 = f0 ? wc0 : bd0;
    bn1 = f1 ? wi1 : bn1;
    bd1 = f1 ? wc1 : bd1;
  }
  float best0 = (bd0 < 0.0f) ? MAXT : bn0 * __builtin_amdgcn_rcpf(fmaxf(bd0, 1e-10f));
  float best1 = (bd1 < 0.0f) ? MAXT : bn1 * __builtin_amdgcn_rcpf(fmaxf(bd1, 1e-10f));

  __syncthreads();                           // all prefix reads of red4 done
  red4[seg][lane] = make_float4(best0, best1, 0.0f, 0.0f);
  __syncthreads();
  if (seg == 0) {
    float4 m = red4[0][lane];
#pragma unroll
    for (int s = 1; s < NSEG; ++s) {
      float4 t = red4[s][lane];
      m.x = fminf(m.x, t.x);
      m.y = fminf(m.y, t.y);
    }
    *(float2*)(&out[b * OUTS + jc * 128 + lane * 2]) = make_float2(m.x, m.y);
  }
}

extern "C" void kernel_launch(void* const* d_in, const int* in_sizes, int n_in,
                              void* d_out, int out_size, void* d_ws, size_t ws_size,
                              hipStream_t stream) {
  const float* layer_in = (const float*)d_in[0];
  const float* weight   = (const float*)d_in[1];
  const float* delay    = (const float*)d_in[2];
  float* out = (float*)d_out;
  (void)d_ws; (void)ws_size;

  snn_fused<<<dim3(B, OUTS / 128), dim3(64, NSEG), 0, stream>>>(
      layer_in, weight, delay, out);
}